// Round 1
// baseline (488.944 us; speedup 1.0000x reference)
//
#include <hip/hip_runtime.h>
#include <stdint.h>

#define B_  16
#define T_  1024
#define D_  1024
#define H_  256
#define R_  64
#define N_  8
#define BT_ (B_ * T_)

typedef unsigned short u16;
typedef __bf16 bf16_t;
typedef bf16_t bf16x8 __attribute__((ext_vector_type(8)));
typedef float f32x4 __attribute__((ext_vector_type(4)));

__device__ __forceinline__ u16 f2bf(float f) {
    union { float f; uint32_t u; } v; v.f = f;
    uint32_t u = v.u;
    u += 0x7FFFu + ((u >> 16) & 1u);   // round-to-nearest-even
    return (u16)(u >> 16);
}

// ---------------- conversion kernels ----------------

__global__ __launch_bounds__(256) void cvt_x_kernel(const float* __restrict__ in,
                                                    u16* __restrict__ outp, int n4) {
    int i = blockIdx.x * 256 + threadIdx.x;
    if (i >= n4) return;
    float4 v = reinterpret_cast<const float4*>(in)[i];
    ushort4 o;
    o.x = f2bf(v.x); o.y = f2bf(v.y); o.z = f2bf(v.z); o.w = f2bf(v.w);
    reinterpret_cast<ushort4*>(outp)[i] = o;
}

// in: fp32 [z][Rr][Cc]  ->  out: bf16 [z][Cc][Rr]   (64x64 LDS tiles)
__global__ __launch_bounds__(256) void transpose_cvt_kernel(const float* __restrict__ in,
                                                            u16* __restrict__ outp,
                                                            int Rr, int Cc) {
    __shared__ u16 tile[64][65];
    const size_t zofs = (size_t)blockIdx.z * Rr * Cc;
    const float* src = in + zofs;
    u16* dst = outp + zofs;
    const int r0 = blockIdx.y * 64, c0 = blockIdx.x * 64;
    const int tx = threadIdx.x & 63, ty = threadIdx.x >> 6;
#pragma unroll
    for (int i = 0; i < 16; i++) {
        int r = i * 4 + ty;
        tile[r][tx] = f2bf(src[(size_t)(r0 + r) * Cc + (c0 + tx)]);
    }
    __syncthreads();
#pragma unroll
    for (int i = 0; i < 16; i++) {
        int r = i * 4 + ty;
        dst[(size_t)(c0 + r) * Rr + (r0 + tx)] = tile[tx][r];
    }
}

// ---------------- fused encoder -> relu -> decoder -> loss ----------------
// grid (BT/64, N), 256 threads (4 waves). Wave-tile 64x64, 16x16x32 bf16 MFMA.
__global__ __launch_bounds__(256) void enc_loss_kernel(
    const u16* __restrict__ xb, const float* __restrict__ x,
    const u16* __restrict__ Wenc_t,   // [N][H][D]  (= W_enc^T per n)
    const float* __restrict__ b_enc,  // [N][H]
    const u16* __restrict__ Wdec_t,   // [N][D][H]  (= W_dec^T per n)
    const float* __restrict__ b_dec,  // [N][D]
    float* __restrict__ losses) {     // [N][B] (pre-zeroed)

    __shared__ u16 lds_a[64 * 32];    // x tile [64][32]
    __shared__ u16 lds_b[256 * 32];   // weight tile [256][32]
    __shared__ u16 lds_h[64 * 264];   // h tile [64][256], stride 264
    __shared__ float red[256];

    const int n = blockIdx.y;
    const int r0 = blockIdx.x * 64;
    const int bsamp = r0 >> 10;       // sample index (64 | 1024, no straddle)
    const int t = threadIdx.x;
    const int w = t >> 6;
    const int l = t & 63;
    const int lr = l & 15;
    const int lq = l >> 4;
    const int lk = lq * 8;

    const u16* We = Wenc_t + (size_t)n * H_ * D_;
    const u16* Wd = Wdec_t + (size_t)n * D_ * H_;

    const f32x4 fzero = {0.f, 0.f, 0.f, 0.f};
    f32x4 acc[4][4];
#pragma unroll
    for (int mt = 0; mt < 4; mt++)
#pragma unroll
        for (int nt = 0; nt < 4; nt++) acc[mt][nt] = fzero;

    // ---- Phase 1: h[64][256] = relu(x @ W_enc + b_enc); wave w owns cols w*64..
    for (int ks = 0; ks < 32; ks++) {
        const int k0 = ks * 32;
        __syncthreads();
        {
            int row = t >> 2, kc = t & 3;
            *reinterpret_cast<uint4*>(&lds_a[row * 32 + kc * 8]) =
                *reinterpret_cast<const uint4*>(&xb[(size_t)(r0 + row) * D_ + k0 + kc * 8]);
        }
#pragma unroll
        for (int i = 0; i < 4; i++) {
            int ch = i * 256 + t;
            int row = ch >> 2, kc = ch & 3;
            *reinterpret_cast<uint4*>(&lds_b[row * 32 + kc * 8]) =
                *reinterpret_cast<const uint4*>(&We[(size_t)row * D_ + k0 + kc * 8]);
        }
        __syncthreads();
        bf16x8 af[4], bfr[4];
#pragma unroll
        for (int mt = 0; mt < 4; mt++)
            af[mt] = *reinterpret_cast<const bf16x8*>(&lds_a[(mt * 16 + lr) * 32 + lk]);
#pragma unroll
        for (int nt = 0; nt < 4; nt++)
            bfr[nt] = *reinterpret_cast<const bf16x8*>(&lds_b[(w * 64 + nt * 16 + lr) * 32 + lk]);
#pragma unroll
        for (int mt = 0; mt < 4; mt++)
#pragma unroll
            for (int nt = 0; nt < 4; nt++)
                acc[mt][nt] = __builtin_amdgcn_mfma_f32_16x16x32_bf16(af[mt], bfr[nt], acc[mt][nt], 0, 0, 0);
    }
    __syncthreads();
#pragma unroll
    for (int mt = 0; mt < 4; mt++)
#pragma unroll
        for (int nt = 0; nt < 4; nt++) {
            int hc = w * 64 + nt * 16 + lr;
            float bias = b_enc[n * H_ + hc];
#pragma unroll
            for (int r = 0; r < 4; r++) {
                int row = mt * 16 + lq * 4 + r;
                float v2 = acc[mt][nt][r] + bias;
                lds_h[row * 264 + hc] = f2bf(v2 > 0.f ? v2 : 0.f);
            }
        }
    __syncthreads();

    // ---- Phase 2: recon[64][1024] = h @ W_dec + b_dec, fused (recon-x)^2
    float lacc = 0.f;
    for (int chk = 0; chk < 4; chk++) {       // 256-wide column chunks of D
#pragma unroll
        for (int mt = 0; mt < 4; mt++)
#pragma unroll
            for (int nt = 0; nt < 4; nt++) acc[mt][nt] = fzero;
        for (int ks = 0; ks < 8; ks++) {      // K = H = 256
            __syncthreads();
#pragma unroll
            for (int i = 0; i < 4; i++) {
                int c2 = i * 256 + t;
                int row = c2 >> 2, kc = c2 & 3;
                *reinterpret_cast<uint4*>(&lds_b[row * 32 + kc * 8]) =
                    *reinterpret_cast<const uint4*>(&Wd[(size_t)(chk * 256 + row) * H_ + ks * 32 + kc * 8]);
            }
            __syncthreads();
            bf16x8 af[4], bfr[4];
#pragma unroll
            for (int mt = 0; mt < 4; mt++)
                af[mt] = *reinterpret_cast<const bf16x8*>(&lds_h[(mt * 16 + lr) * 264 + ks * 32 + lk]);
#pragma unroll
            for (int nt = 0; nt < 4; nt++)
                bfr[nt] = *reinterpret_cast<const bf16x8*>(&lds_b[(w * 64 + nt * 16 + lr) * 32 + lk]);
#pragma unroll
            for (int mt = 0; mt < 4; mt++)
#pragma unroll
                for (int nt = 0; nt < 4; nt++)
                    acc[mt][nt] = __builtin_amdgcn_mfma_f32_16x16x32_bf16(af[mt], bfr[nt], acc[mt][nt], 0, 0, 0);
        }
#pragma unroll
        for (int mt = 0; mt < 4; mt++)
#pragma unroll
            for (int nt = 0; nt < 4; nt++) {
                int d = chk * 256 + w * 64 + nt * 16 + lr;
                float bias = b_dec[n * D_ + d];
#pragma unroll
                for (int r = 0; r < 4; r++) {
                    int row = mt * 16 + lq * 4 + r;
                    float recon = acc[mt][nt][r] + bias;
                    float diff = recon - x[(size_t)(r0 + row) * D_ + d];
                    lacc += diff * diff;
                }
            }
    }

    red[t] = lacc;
    __syncthreads();
    for (int s = 128; s > 0; s >>= 1) {
        if (t < s) red[t] += red[t + s];
        __syncthreads();
    }
    if (t == 0) atomicAdd(&losses[n * B_ + bsamp], red[0]);
}

// ---------------- argmin routing ----------------
__global__ void argmin_kernel(const float* __restrict__ losses,
                              const int* __restrict__ cidx,
                              int* __restrict__ adp) {
    int b = threadIdx.x;
    if (b < B_) {
        float best = losses[b];
        int bi = 0;
        for (int n = 1; n < N_; n++) {
            float v = losses[n * B_ + b];
            if (v < best) { best = v; bi = n; }   // strict < : first-min like jnp.argmin
        }
        adp[b] = cidx[bi];
    }
}

// ---------------- mid = relu(x @ W_down[adp] + b_down) ----------------
// grid BT/64, one wave per block; wave-tile 64x64 (R=64).
__global__ __launch_bounds__(64) void down_kernel(
    const u16* __restrict__ xb,
    const u16* __restrict__ Wdown_t,  // [N][R][D]
    const float* __restrict__ b_down, // [N][R]
    const int* __restrict__ adp,
    u16* __restrict__ mid) {          // [BT][R] bf16
    __shared__ u16 lds_a[64 * 32];
    __shared__ u16 lds_b[64 * 32];
    const int r0 = blockIdx.x * 64;
    const int n = adp[r0 >> 10];
    const u16* Wd = Wdown_t + (size_t)n * R_ * D_;
    const int l = threadIdx.x;
    const int lr = l & 15, lq = l >> 4, lk = lq * 8;
    const f32x4 fzero = {0.f, 0.f, 0.f, 0.f};
    f32x4 acc[4][4];
#pragma unroll
    for (int mt = 0; mt < 4; mt++)
#pragma unroll
        for (int nt = 0; nt < 4; nt++) acc[mt][nt] = fzero;
    for (int ks = 0; ks < 32; ks++) {
        const int k0 = ks * 32;
        __syncthreads();
#pragma unroll
        for (int i = 0; i < 4; i++) {
            int ch = i * 64 + l;
            int row = ch >> 2, kc = ch & 3;
            *reinterpret_cast<uint4*>(&lds_a[row * 32 + kc * 8]) =
                *reinterpret_cast<const uint4*>(&xb[(size_t)(r0 + row) * D_ + k0 + kc * 8]);
            *reinterpret_cast<uint4*>(&lds_b[row * 32 + kc * 8]) =
                *reinterpret_cast<const uint4*>(&Wd[(size_t)row * D_ + k0 + kc * 8]);
        }
        __syncthreads();
        bf16x8 af[4], bfr[4];
#pragma unroll
        for (int mt = 0; mt < 4; mt++)
            af[mt] = *reinterpret_cast<const bf16x8*>(&lds_a[(mt * 16 + lr) * 32 + lk]);
#pragma unroll
        for (int nt = 0; nt < 4; nt++)
            bfr[nt] = *reinterpret_cast<const bf16x8*>(&lds_b[(nt * 16 + lr) * 32 + lk]);
#pragma unroll
        for (int mt = 0; mt < 4; mt++)
#pragma unroll
            for (int nt = 0; nt < 4; nt++)
                acc[mt][nt] = __builtin_amdgcn_mfma_f32_16x16x32_bf16(af[mt], bfr[nt], acc[mt][nt], 0, 0, 0);
    }
#pragma unroll
    for (int mt = 0; mt < 4; mt++)
#pragma unroll
        for (int nt = 0; nt < 4; nt++) {
            int col = nt * 16 + lr;
            float bias = b_down[n * R_ + col];
#pragma unroll
            for (int r = 0; r < 4; r++) {
                int row = mt * 16 + lq * 4 + r;
                float v2 = acc[mt][nt][r] + bias;
                mid[(size_t)(r0 + row) * R_ + col] = f2bf(v2 > 0.f ? v2 : 0.f);
            }
        }
}

// ---------------- out = x@W_base + mid@W_up[adp] + b_base + b_up[adp] ----------------
// grid (D/128, BT/128), 256 threads, waves 2x2 over a 128x128 tile.
__global__ __launch_bounds__(256) void out_kernel(
    const u16* __restrict__ xb,
    const u16* __restrict__ Wb_t,     // [D][D] = W_base^T
    const float* __restrict__ b_base, // [D]
    const u16* __restrict__ mid,      // [BT][R]
    const u16* __restrict__ Wup_t,    // [N][D][R] = W_up^T per n
    const float* __restrict__ b_up,   // [N][D]
    const int* __restrict__ adp,
    float* __restrict__ outp) {       // [BT][D] fp32
    __shared__ u16 lds_a[128 * 32];
    __shared__ u16 lds_b[128 * 32];
    const int c0 = blockIdx.x * 128;
    const int r0 = blockIdx.y * 128;
    const int n = adp[r0 >> 10];
    const int t = threadIdx.x, w = t >> 6, l = t & 63;
    const int wm = (w >> 1) * 64, wn = (w & 1) * 64;
    const int lr = l & 15, lq = l >> 4, lk = lq * 8;
    const f32x4 fzero = {0.f, 0.f, 0.f, 0.f};
    f32x4 acc[4][4];
#pragma unroll
    for (int mt = 0; mt < 4; mt++)
#pragma unroll
        for (int nt = 0; nt < 4; nt++) acc[mt][nt] = fzero;

    // Phase A: K = D over x / W_base^T
    for (int ks = 0; ks < 32; ks++) {
        const int k0 = ks * 32;
        __syncthreads();
#pragma unroll
        for (int i = 0; i < 2; i++) {
            int ch = i * 256 + t;
            int row = ch >> 2, kc = ch & 3;
            *reinterpret_cast<uint4*>(&lds_a[row * 32 + kc * 8]) =
                *reinterpret_cast<const uint4*>(&xb[(size_t)(r0 + row) * D_ + k0 + kc * 8]);
            *reinterpret_cast<uint4*>(&lds_b[row * 32 + kc * 8]) =
                *reinterpret_cast<const uint4*>(&Wb_t[(size_t)(c0 + row) * D_ + k0 + kc * 8]);
        }
        __syncthreads();
        bf16x8 af[4], bfr[4];
#pragma unroll
        for (int mt = 0; mt < 4; mt++)
            af[mt] = *reinterpret_cast<const bf16x8*>(&lds_a[(wm + mt * 16 + lr) * 32 + lk]);
#pragma unroll
        for (int nt = 0; nt < 4; nt++)
            bfr[nt] = *reinterpret_cast<const bf16x8*>(&lds_b[(wn + nt * 16 + lr) * 32 + lk]);
#pragma unroll
        for (int mt = 0; mt < 4; mt++)
#pragma unroll
            for (int nt = 0; nt < 4; nt++)
                acc[mt][nt] = __builtin_amdgcn_mfma_f32_16x16x32_bf16(af[mt], bfr[nt], acc[mt][nt], 0, 0, 0);
    }

    // Phase B: K = R over mid / W_up^T[n]
    const u16* Wu = Wup_t + (size_t)n * D_ * R_;
    for (int ks = 0; ks < 2; ks++) {
        const int k0 = ks * 32;
        __syncthreads();
#pragma unroll
        for (int i = 0; i < 2; i++) {
            int ch = i * 256 + t;
            int row = ch >> 2, kc = ch & 3;
            *reinterpret_cast<uint4*>(&lds_a[row * 32 + kc * 8]) =
                *reinterpret_cast<const uint4*>(&mid[(size_t)(r0 + row) * R_ + k0 + kc * 8]);
            *reinterpret_cast<uint4*>(&lds_b[row * 32 + kc * 8]) =
                *reinterpret_cast<const uint4*>(&Wu[(size_t)(c0 + row) * R_ + k0 + kc * 8]);
        }
        __syncthreads();
        bf16x8 af[4], bfr[4];
#pragma unroll
        for (int mt = 0; mt < 4; mt++)
            af[mt] = *reinterpret_cast<const bf16x8*>(&lds_a[(wm + mt * 16 + lr) * 32 + lk]);
#pragma unroll
        for (int nt = 0; nt < 4; nt++)
            bfr[nt] = *reinterpret_cast<const bf16x8*>(&lds_b[(wn + nt * 16 + lr) * 32 + lk]);
#pragma unroll
        for (int mt = 0; mt < 4; mt++)
#pragma unroll
            for (int nt = 0; nt < 4; nt++)
                acc[mt][nt] = __builtin_amdgcn_mfma_f32_16x16x32_bf16(af[mt], bfr[nt], acc[mt][nt], 0, 0, 0);
    }

#pragma unroll
    for (int mt = 0; mt < 4; mt++)
#pragma unroll
        for (int nt = 0; nt < 4; nt++) {
            int gc = c0 + wn + nt * 16 + lr;
            float bias = b_base[gc] + b_up[n * D_ + gc];
#pragma unroll
            for (int r = 0; r < 4; r++) {
                int row = r0 + wm + mt * 16 + lq * 4 + r;
                outp[(size_t)row * D_ + gc] = acc[mt][nt][r] + bias;
            }
        }
}

// ---------------- launch ----------------
extern "C" void kernel_launch(void* const* d_in, const int* in_sizes, int n_in,
                              void* d_out, int out_size, void* d_ws, size_t ws_size,
                              hipStream_t stream) {
    const float* x      = (const float*)d_in[0];
    const float* W_base = (const float*)d_in[1];
    const float* b_base = (const float*)d_in[2];
    const float* W_enc  = (const float*)d_in[3];
    const float* b_enc  = (const float*)d_in[4];
    const float* W_dec  = (const float*)d_in[5];
    const float* b_dec  = (const float*)d_in[6];
    const float* W_down = (const float*)d_in[7];
    const float* b_down = (const float*)d_in[8];
    const float* W_up   = (const float*)d_in[9];
    const float* b_up   = (const float*)d_in[10];
    const int*   cidx   = (const int*)d_in[11];
    float* outp = (float*)d_out;
    (void)in_sizes; (void)n_in; (void)out_size; (void)ws_size;

    char* p = (char*)d_ws;
    u16* xb      = (u16*)p; p += (size_t)BT_ * D_ * 2;      // 32 MB
    u16* Wb_t    = (u16*)p; p += (size_t)D_ * D_ * 2;       // 2 MB
    u16* Wenc_t  = (u16*)p; p += (size_t)N_ * H_ * D_ * 2;  // 4 MB
    u16* Wdec_t  = (u16*)p; p += (size_t)N_ * D_ * H_ * 2;  // 4 MB
    u16* Wdown_t = (u16*)p; p += (size_t)N_ * R_ * D_ * 2;  // 1 MB
    u16* Wup_t   = (u16*)p; p += (size_t)N_ * D_ * R_ * 2;  // 1 MB
    u16* mid     = (u16*)p; p += (size_t)BT_ * R_ * 2;      // 2 MB
    float* losses = (float*)p; p += 256;
    int* adp      = (int*)p; p += 256;

    hipMemsetAsync(losses, 0, N_ * B_ * sizeof(float), stream);

    cvt_x_kernel<<<(BT_ * D_ / 4 + 255) / 256, 256, 0, stream>>>(x, xb, BT_ * D_ / 4);
    transpose_cvt_kernel<<<dim3(D_ / 64, D_ / 64, 1),  256, 0, stream>>>(W_base, Wb_t,    D_, D_);
    transpose_cvt_kernel<<<dim3(H_ / 64, D_ / 64, N_), 256, 0, stream>>>(W_enc,  Wenc_t,  D_, H_);
    transpose_cvt_kernel<<<dim3(D_ / 64, H_ / 64, N_), 256, 0, stream>>>(W_dec,  Wdec_t,  H_, D_);
    transpose_cvt_kernel<<<dim3(R_ / 64, D_ / 64, N_), 256, 0, stream>>>(W_down, Wdown_t, D_, R_);
    transpose_cvt_kernel<<<dim3(D_ / 64, R_ / 64, N_), 256, 0, stream>>>(W_up,   Wup_t,   R_, D_);

    enc_loss_kernel<<<dim3(BT_ / 64, N_), 256, 0, stream>>>(xb, x, Wenc_t, b_enc, Wdec_t, b_dec, losses);
    argmin_kernel<<<1, 64, 0, stream>>>(losses, cidx, adp);
    down_kernel<<<BT_ / 64, 64, 0, stream>>>(xb, Wdown_t, b_down, adp, mid);
    out_kernel<<<dim3(D_ / 128, BT_ / 128), 256, 0, stream>>>(xb, Wb_t, b_base, mid, Wup_t, b_up, adp, outp);
}

// Round 2
// 456.733 us; speedup vs baseline: 1.0705x; 1.0705x over previous
//
#include <hip/hip_runtime.h>
#include <stdint.h>

#define B_  16
#define T_  1024
#define D_  1024
#define H_  256
#define R_  64
#define N_  8
#define BT_ (B_ * T_)

typedef unsigned short u16;
typedef __bf16 bf16_t;
typedef bf16_t bf16x8 __attribute__((ext_vector_type(8)));
typedef float f32x4 __attribute__((ext_vector_type(4)));

__device__ __forceinline__ u16 f2bf(float f) {
    union { float f; uint32_t u; } v; v.f = f;
    uint32_t u = v.u;
    u += 0x7FFFu + ((u >> 16) & 1u);   // round-to-nearest-even
    return (u16)(u >> 16);
}

// async global->LDS, 16B per lane; LDS dest is wave-uniform base + lane*16
__device__ __forceinline__ void gl_lds16(const void* g, void* l) {
    __builtin_amdgcn_global_load_lds(
        (const __attribute__((address_space(1))) void*)g,
        (__attribute__((address_space(3))) void*)l, 16, 0, 0);
}

// ---------------- conversion kernels ----------------

__global__ __launch_bounds__(256) void cvt_x_kernel(const float* __restrict__ in,
                                                    u16* __restrict__ outp, int n4) {
    int i = blockIdx.x * 256 + threadIdx.x;
    if (i >= n4) return;
    float4 v = reinterpret_cast<const float4*>(in)[i];
    ushort4 o;
    o.x = f2bf(v.x); o.y = f2bf(v.y); o.z = f2bf(v.z); o.w = f2bf(v.w);
    reinterpret_cast<ushort4*>(outp)[i] = o;
}

// in: fp32 [z][Rr][Cc]  ->  out: bf16 [z][Cc][Rr]   (64x64 LDS tiles)
__global__ __launch_bounds__(256) void transpose_cvt_kernel(const float* __restrict__ in,
                                                            u16* __restrict__ outp,
                                                            int Rr, int Cc) {
    __shared__ u16 tile[64][65];
    const size_t zofs = (size_t)blockIdx.z * Rr * Cc;
    const float* src = in + zofs;
    u16* dst = outp + zofs;
    const int r0 = blockIdx.y * 64, c0 = blockIdx.x * 64;
    const int tx = threadIdx.x & 63, ty = threadIdx.x >> 6;
#pragma unroll
    for (int i = 0; i < 16; i++) {
        int r = i * 4 + ty;
        tile[r][tx] = f2bf(src[(size_t)(r0 + r) * Cc + (c0 + tx)]);
    }
    __syncthreads();
#pragma unroll
    for (int i = 0; i < 16; i++) {
        int r = i * 4 + ty;
        dst[(size_t)(c0 + r) * Rr + (r0 + tx)] = tile[tx][r];
    }
}

// ---------------- fused encoder -> relu -> decoder -> loss ----------------
// grid (BT/64, N), 256 threads (4 waves). Wave-tile 64x64, 16x16x32 bf16 MFMA.
// Staging via global_load_lds width=16 (m97 ladder step).
__global__ __launch_bounds__(256) void enc_loss_kernel(
    const u16* __restrict__ xb, const float* __restrict__ x,
    const u16* __restrict__ Wenc_t,   // [N][H][D]
    const float* __restrict__ b_enc,  // [N][H]
    const u16* __restrict__ Wdec_t,   // [N][D][H]
    const float* __restrict__ b_dec,  // [N][D]
    float* __restrict__ losses) {     // [N][B] pre-zeroed

    __shared__ u16 lds_a[64 * 32];    // 4 KB
    __shared__ u16 lds_b[256 * 32];   // 16 KB
    __shared__ u16 lds_h[64 * 264];   // ~33 KB
    __shared__ float red[256];

    const int n = blockIdx.y;
    const int r0 = blockIdx.x * 64;
    const int bsamp = r0 >> 10;
    const int t = threadIdx.x;
    const int w = t >> 6;
    const int l = t & 63;
    const int lr = l & 15;
    const int lq = l >> 4;
    const int lk = lq * 8;

    const u16* We = Wenc_t + (size_t)n * H_ * D_;
    const u16* Wd = Wdec_t + (size_t)n * D_ * H_;

    const f32x4 fzero = {0.f, 0.f, 0.f, 0.f};
    f32x4 acc[4][4];
#pragma unroll
    for (int mt = 0; mt < 4; mt++)
#pragma unroll
        for (int nt = 0; nt < 4; nt++) acc[mt][nt] = fzero;

    // ---- Phase 1: h[64][256] = relu(x @ W_enc^T + b_enc)
    for (int ks = 0; ks < 32; ks++) {
        const int k0 = ks * 32;
        __syncthreads();
        {   // A tile: 4 KB = 4 chunks of 1 KB, one per wave
            int c = w * 64 + l, row = c >> 2, kc = c & 3;
            gl_lds16(&xb[(size_t)(r0 + row) * D_ + k0 + kc * 8],
                     (char*)lds_a + w * 1024);
        }
#pragma unroll
        for (int i = 0; i < 4; i++) {   // B tile: 16 KB = 16 chunks
            int j = w * 4 + i;
            int c = j * 64 + l, row = c >> 2, kc = c & 3;
            gl_lds16(&We[(size_t)row * D_ + k0 + kc * 8],
                     (char*)lds_b + j * 1024);
        }
        __syncthreads();
        bf16x8 af[4], bfr[4];
#pragma unroll
        for (int mt = 0; mt < 4; mt++)
            af[mt] = *reinterpret_cast<const bf16x8*>(&lds_a[(mt * 16 + lr) * 32 + lk]);
#pragma unroll
        for (int nt = 0; nt < 4; nt++)
            bfr[nt] = *reinterpret_cast<const bf16x8*>(&lds_b[(w * 64 + nt * 16 + lr) * 32 + lk]);
#pragma unroll
        for (int mt = 0; mt < 4; mt++)
#pragma unroll
            for (int nt = 0; nt < 4; nt++)
                acc[mt][nt] = __builtin_amdgcn_mfma_f32_16x16x32_bf16(af[mt], bfr[nt], acc[mt][nt], 0, 0, 0);
    }
    __syncthreads();
#pragma unroll
    for (int mt = 0; mt < 4; mt++)
#pragma unroll
        for (int nt = 0; nt < 4; nt++) {
            int hc = w * 64 + nt * 16 + lr;
            float bias = b_enc[n * H_ + hc];
#pragma unroll
            for (int r = 0; r < 4; r++) {
                int row = mt * 16 + lq * 4 + r;
                float v2 = acc[mt][nt][r] + bias;
                lds_h[row * 264 + hc] = f2bf(v2 > 0.f ? v2 : 0.f);
            }
        }
    __syncthreads();

    // ---- Phase 2: recon[64][1024] = h @ W_dec^T + b_dec, fused (recon-x)^2
    float lacc = 0.f;
    for (int chk = 0; chk < 4; chk++) {
#pragma unroll
        for (int mt = 0; mt < 4; mt++)
#pragma unroll
            for (int nt = 0; nt < 4; nt++) acc[mt][nt] = fzero;
        for (int ks = 0; ks < 8; ks++) {
            __syncthreads();
#pragma unroll
            for (int i = 0; i < 4; i++) {
                int j = w * 4 + i;
                int c = j * 64 + l, row = c >> 2, kc = c & 3;
                gl_lds16(&Wd[(size_t)(chk * 256 + row) * H_ + ks * 32 + kc * 8],
                         (char*)lds_b + j * 1024);
            }
            __syncthreads();
            bf16x8 af[4], bfr[4];
#pragma unroll
            for (int mt = 0; mt < 4; mt++)
                af[mt] = *reinterpret_cast<const bf16x8*>(&lds_h[(mt * 16 + lr) * 264 + ks * 32 + lk]);
#pragma unroll
            for (int nt = 0; nt < 4; nt++)
                bfr[nt] = *reinterpret_cast<const bf16x8*>(&lds_b[(w * 64 + nt * 16 + lr) * 32 + lk]);
#pragma unroll
            for (int mt = 0; mt < 4; mt++)
#pragma unroll
                for (int nt = 0; nt < 4; nt++)
                    acc[mt][nt] = __builtin_amdgcn_mfma_f32_16x16x32_bf16(af[mt], bfr[nt], acc[mt][nt], 0, 0, 0);
        }
#pragma unroll
        for (int mt = 0; mt < 4; mt++)
#pragma unroll
            for (int nt = 0; nt < 4; nt++) {
                int d = chk * 256 + w * 64 + nt * 16 + lr;
                float bias = b_dec[n * D_ + d];
#pragma unroll
                for (int r = 0; r < 4; r++) {
                    int row = mt * 16 + lq * 4 + r;
                    float recon = acc[mt][nt][r] + bias;
                    float diff = recon - x[(size_t)(r0 + row) * D_ + d];
                    lacc += diff * diff;
                }
            }
    }

    red[t] = lacc;
    __syncthreads();
    for (int s = 128; s > 0; s >>= 1) {
        if (t < s) red[t] += red[t + s];
        __syncthreads();
    }
    if (t == 0) atomicAdd(&losses[n * B_ + bsamp], red[0]);
}

// ---------------- argmin routing ----------------
__global__ void argmin_kernel(const float* __restrict__ losses,
                              const int* __restrict__ cidx,
                              int* __restrict__ adp) {
    int b = threadIdx.x;
    if (b < B_) {
        float best = losses[b];
        int bi = 0;
        for (int n = 1; n < N_; n++) {
            float v = losses[n * B_ + b];
            if (v < best) { best = v; bi = n; }
        }
        adp[b] = cidx[bi];
    }
}

// ---------------- mid = relu(x @ W_down[adp]^T + b_down) ----------------
// grid BT/64, 256 threads (4 waves), K-split across waves (K/4 = 256 each),
// per-wave private LDS staging + async load, f32 partial reduce.
__global__ __launch_bounds__(256) void down_kernel(
    const u16* __restrict__ xb,
    const u16* __restrict__ Wdown_t,  // [N][R][D]
    const float* __restrict__ b_down, // [N][R]
    const int* __restrict__ adp,
    u16* __restrict__ mid) {          // [BT][R] bf16
    __shared__ char smem[65536];      // staging (4 waves x 8KB) then f32 partials (64KB)
    const int r0 = blockIdx.x * 64;
    const int n = adp[r0 >> 10];
    const u16* Wd = Wdown_t + (size_t)n * R_ * D_;
    const int t = threadIdx.x, w = t >> 6, l = t & 63;
    const int lr = l & 15, lq = l >> 4, lk = lq * 8;
    char* wbase = smem + w * 8192;
    const u16* sa = (const u16*)wbase;
    const u16* sb = (const u16*)(wbase + 4096);
    const f32x4 fzero = {0.f, 0.f, 0.f, 0.f};
    f32x4 acc[4][4];
#pragma unroll
    for (int mt = 0; mt < 4; mt++)
#pragma unroll
        for (int nt = 0; nt < 4; nt++) acc[mt][nt] = fzero;

    for (int ks2 = 0; ks2 < 8; ks2++) {
        const int k0 = (w * 8 + ks2) * 32;
        __syncthreads();
#pragma unroll
        for (int i = 0; i < 4; i++) {
            int c = i * 64 + l, row = c >> 2, kc = c & 3;
            gl_lds16(&xb[(size_t)(r0 + row) * D_ + k0 + kc * 8], wbase + i * 1024);
            gl_lds16(&Wd[(size_t)row * D_ + k0 + kc * 8], wbase + 4096 + i * 1024);
        }
        __syncthreads();
        bf16x8 af[4], bfr[4];
#pragma unroll
        for (int mt = 0; mt < 4; mt++)
            af[mt] = *reinterpret_cast<const bf16x8*>(&sa[(mt * 16 + lr) * 32 + lk]);
#pragma unroll
        for (int nt = 0; nt < 4; nt++)
            bfr[nt] = *reinterpret_cast<const bf16x8*>(&sb[(nt * 16 + lr) * 32 + lk]);
#pragma unroll
        for (int mt = 0; mt < 4; mt++)
#pragma unroll
            for (int nt = 0; nt < 4; nt++)
                acc[mt][nt] = __builtin_amdgcn_mfma_f32_16x16x32_bf16(af[mt], bfr[nt], acc[mt][nt], 0, 0, 0);
    }

    __syncthreads();
    float* pr = (float*)smem;         // [4][64*64] partials
#pragma unroll
    for (int mt = 0; mt < 4; mt++)
#pragma unroll
        for (int nt = 0; nt < 4; nt++)
#pragma unroll
            for (int r = 0; r < 4; r++)
                pr[w * 4096 + (mt * 16 + lq * 4 + r) * 64 + nt * 16 + lr] = acc[mt][nt][r];
    __syncthreads();
#pragma unroll
    for (int ei = 0; ei < 16; ei++) {
        int e = ei * 256 + t;
        float s = pr[e] + pr[4096 + e] + pr[8192 + e] + pr[12288 + e];
        int row = e >> 6, col = e & 63;
        float v = s + b_down[n * R_ + col];
        mid[(size_t)(r0 + row) * R_ + col] = f2bf(v > 0.f ? v : 0.f);
    }
}

// ---------------- out = x@W_base + mid@W_up[adp] + b_base + b_up[adp] ----------------
// grid (D/128, BT/128), 256 threads, waves 2x2 over 128x128 tile; async staging.
__global__ __launch_bounds__(256) void out_kernel(
    const u16* __restrict__ xb,
    const u16* __restrict__ Wb_t,     // [D][D] = W_base^T
    const float* __restrict__ b_base, // [D]
    const u16* __restrict__ mid,      // [BT][R]
    const u16* __restrict__ Wup_t,    // [N][D][R]
    const float* __restrict__ b_up,   // [N][D]
    const int* __restrict__ adp,
    float* __restrict__ outp) {       // [BT][D] fp32
    __shared__ u16 lds_a[128 * 32];   // 8 KB
    __shared__ u16 lds_b[128 * 32];   // 8 KB
    const int c0 = blockIdx.x * 128;
    const int r0 = blockIdx.y * 128;
    const int n = adp[r0 >> 10];
    const int t = threadIdx.x, w = t >> 6, l = t & 63;
    const int wm = (w >> 1) * 64, wn = (w & 1) * 64;
    const int lr = l & 15, lq = l >> 4, lk = lq * 8;
    const f32x4 fzero = {0.f, 0.f, 0.f, 0.f};
    f32x4 acc[4][4];
#pragma unroll
    for (int mt = 0; mt < 4; mt++)
#pragma unroll
        for (int nt = 0; nt < 4; nt++) acc[mt][nt] = fzero;

    // Phase A: K = D over x / W_base^T
    for (int ks = 0; ks < 32; ks++) {
        const int k0 = ks * 32;
        __syncthreads();
#pragma unroll
        for (int i = 0; i < 2; i++) {
            int j = w * 2 + i;
            int c = j * 64 + l, row = c >> 2, kc = c & 3;
            gl_lds16(&xb[(size_t)(r0 + row) * D_ + k0 + kc * 8],
                     (char*)lds_a + j * 1024);
            gl_lds16(&Wb_t[(size_t)(c0 + row) * D_ + k0 + kc * 8],
                     (char*)lds_b + j * 1024);
        }
        __syncthreads();
        bf16x8 af[4], bfr[4];
#pragma unroll
        for (int mt = 0; mt < 4; mt++)
            af[mt] = *reinterpret_cast<const bf16x8*>(&lds_a[(wm + mt * 16 + lr) * 32 + lk]);
#pragma unroll
        for (int nt = 0; nt < 4; nt++)
            bfr[nt] = *reinterpret_cast<const bf16x8*>(&lds_b[(wn + nt * 16 + lr) * 32 + lk]);
#pragma unroll
        for (int mt = 0; mt < 4; mt++)
#pragma unroll
            for (int nt = 0; nt < 4; nt++)
                acc[mt][nt] = __builtin_amdgcn_mfma_f32_16x16x32_bf16(af[mt], bfr[nt], acc[mt][nt], 0, 0, 0);
    }

    // Phase B: K = R over mid / W_up^T[n]
    const u16* Wu = Wup_t + (size_t)n * D_ * R_;
    for (int ks = 0; ks < 2; ks++) {
        const int k0 = ks * 32;
        __syncthreads();
#pragma unroll
        for (int i = 0; i < 2; i++) {
            int j = w * 2 + i;
            int c = j * 64 + l, row = c >> 2, kc = c & 3;
            gl_lds16(&mid[(size_t)(r0 + row) * R_ + k0 + kc * 8],
                     (char*)lds_a + j * 1024);
            gl_lds16(&Wu[(size_t)(c0 + row) * R_ + k0 + kc * 8],
                     (char*)lds_b + j * 1024);
        }
        __syncthreads();
        bf16x8 af[4], bfr[4];
#pragma unroll
        for (int mt = 0; mt < 4; mt++)
            af[mt] = *reinterpret_cast<const bf16x8*>(&lds_a[(wm + mt * 16 + lr) * 32 + lk]);
#pragma unroll
        for (int nt = 0; nt < 4; nt++)
            bfr[nt] = *reinterpret_cast<const bf16x8*>(&lds_b[(wn + nt * 16 + lr) * 32 + lk]);
#pragma unroll
        for (int mt = 0; mt < 4; mt++)
#pragma unroll
            for (int nt = 0; nt < 4; nt++)
                acc[mt][nt] = __builtin_amdgcn_mfma_f32_16x16x32_bf16(af[mt], bfr[nt], acc[mt][nt], 0, 0, 0);
    }

#pragma unroll
    for (int mt = 0; mt < 4; mt++)
#pragma unroll
        for (int nt = 0; nt < 4; nt++) {
            int gc = c0 + wn + nt * 16 + lr;
            float bias = b_base[gc] + b_up[n * D_ + gc];
#pragma unroll
            for (int r = 0; r < 4; r++) {
                int row = r0 + wm + mt * 16 + lq * 4 + r;
                outp[(size_t)row * D_ + gc] = acc[mt][nt][r] + bias;
            }
        }
}

// ---------------- launch ----------------
extern "C" void kernel_launch(void* const* d_in, const int* in_sizes, int n_in,
                              void* d_out, int out_size, void* d_ws, size_t ws_size,
                              hipStream_t stream) {
    const float* x      = (const float*)d_in[0];
    const float* W_base = (const float*)d_in[1];
    const float* b_base = (const float*)d_in[2];
    const float* W_enc  = (const float*)d_in[3];
    const float* b_enc  = (const float*)d_in[4];
    const float* W_dec  = (const float*)d_in[5];
    const float* b_dec  = (const float*)d_in[6];
    const float* W_down = (const float*)d_in[7];
    const float* b_down = (const float*)d_in[8];
    const float* W_up   = (const float*)d_in[9];
    const float* b_up   = (const float*)d_in[10];
    const int*   cidx   = (const int*)d_in[11];
    float* outp = (float*)d_out;
    (void)in_sizes; (void)n_in; (void)out_size; (void)ws_size;

    char* p = (char*)d_ws;
    u16* xb      = (u16*)p; p += (size_t)BT_ * D_ * 2;
    u16* Wb_t    = (u16*)p; p += (size_t)D_ * D_ * 2;
    u16* Wenc_t  = (u16*)p; p += (size_t)N_ * H_ * D_ * 2;
    u16* Wdec_t  = (u16*)p; p += (size_t)N_ * D_ * H_ * 2;
    u16* Wdown_t = (u16*)p; p += (size_t)N_ * R_ * D_ * 2;
    u16* Wup_t   = (u16*)p; p += (size_t)N_ * D_ * R_ * 2;
    u16* mid     = (u16*)p; p += (size_t)BT_ * R_ * 2;
    float* losses = (float*)p; p += 256;
    int* adp      = (int*)p; p += 256;

    hipMemsetAsync(losses, 0, N_ * B_ * sizeof(float), stream);

    cvt_x_kernel<<<(BT_ * D_ / 4 + 255) / 256, 256, 0, stream>>>(x, xb, BT_ * D_ / 4);
    transpose_cvt_kernel<<<dim3(D_ / 64, D_ / 64, 1),  256, 0, stream>>>(W_base, Wb_t,    D_, D_);
    transpose_cvt_kernel<<<dim3(H_ / 64, D_ / 64, N_), 256, 0, stream>>>(W_enc,  Wenc_t,  D_, H_);
    transpose_cvt_kernel<<<dim3(D_ / 64, H_ / 64, N_), 256, 0, stream>>>(W_dec,  Wdec_t,  H_, D_);
    transpose_cvt_kernel<<<dim3(R_ / 64, D_ / 64, N_), 256, 0, stream>>>(W_down, Wdown_t, D_, R_);
    transpose_cvt_kernel<<<dim3(D_ / 64, R_ / 64, N_), 256, 0, stream>>>(W_up,   Wup_t,   R_, D_);

    enc_loss_kernel<<<dim3(BT_ / 64, N_), 256, 0, stream>>>(xb, x, Wenc_t, b_enc, Wdec_t, b_dec, losses);
    argmin_kernel<<<1, 64, 0, stream>>>(losses, cidx, adp);
    down_kernel<<<BT_ / 64, 256, 0, stream>>>(xb, Wdown_t, b_down, adp, mid);
    out_kernel<<<dim3(D_ / 128, BT_ / 128), 256, 0, stream>>>(xb, Wb_t, b_base, mid, Wup_t, b_up, adp, outp);
}